// Round 6
// baseline (562.493 us; speedup 1.0000x reference)
//
#include <hip/hip_runtime.h>
#include <hip/hip_bf16.h>
#include <math.h>

#define WW     160
#define NBATCH 4
#define VOL    (160*160*160)      // 4,096,000
#define PLANE  (160*160)

#define C1f 0.0001f
#define C2f 0.0009f

#define RUN_H 16                  // h outputs per k_wh block
#define NROWS (RUN_H + 10)        // 26 rows staged
#define LPAD  8                   // left pad (16B-aligns the data region)
#define LDW   180                 // 8 pad | 160 data | 12 pad
#define RUN_D 40                  // d outputs per k_dssim block (4 segments)
#define ITERS (RUN_D + 10)        // 50
#define PF    8                   // prefetch slots; 8 loads in flight per wave

typedef float v2f __attribute__((ext_vector_type(2)));
typedef unsigned long long u64;

struct Gw { float g[11]; };

__device__ __forceinline__ float bf2f(unsigned short u) {
    return __uint_as_float(((unsigned int)u) << 16);
}
__device__ __forceinline__ unsigned short f2bf(float f) {
    __hip_bfloat16 h = __float2bfloat16(f);   // RNE
    return *reinterpret_cast<unsigned short*>(&h);
}

// ---------------- Pass A: W+H conv fused; bf16x2-packed LDS tile ----------------
// Output: 4 bf16 channels per point: {mu1, mu2, conv(x^2)+conv(y^2), conv(xy)}
// block 192 (3 waves; threads 0..159 compute, all 192 load)
// grid (10, d=160, batch=4) = 6400 blocks; LDS 18.7 KB -> 8 blocks/CU.
// CHANGE vs R2/R5: staging vectorized (float4 global loads + uint4 LDS writes).
// The old scalar staging was ~600 VALU/wave (24 iters x magic-div/bounds/pack)
// = 15% of all VALU for 1.5% of the work (G13). Data region starts at col 8 so
// ds_write_b128 targets are 16B-aligned (row stride 180*4=720 = 0 mod 16).
// Taps shift: input col w+k-5 lives at tile col w+k+3.
// Rings: R2's f32 v2f form (measured best; R5's bf16 rings were null).
__global__ __launch_bounds__(192, 4) void k_wh(
    const float* __restrict__ x, const float* __restrict__ y,
    ushort4* __restrict__ B4, Gw gw)
{
    __shared__ unsigned int tile[NROWS][LDW];   // 26*180*4 = 18720 B
    const int t  = threadIdx.x;
    const int h0 = blockIdx.x * RUN_H;
    const int d  = blockIdx.y;
    const int n  = blockIdx.z;

    const float* xb = x + (size_t)n * VOL + (size_t)d * PLANE;
    const float* yb = y + (size_t)n * VOL + (size_t)d * PLANE;

    // ---- zero the pad columns: 26 rows x 20 pad cols (0..7, 168..179) ----
#pragma unroll
    for (int s = t; s < NROWS * 20; s += 192) {
        int r = s / 20, q = s - r * 20;
        int c = (q < 8) ? q : (160 + q);      // q=8..19 -> cols 168..179
        tile[r][c] = 0u;
    }
    // ---- data region: 26 rows x 40 float4 groups, 16B loads + 16B LDS writes ----
#pragma unroll
    for (int s = t; s < NROWS * 40; s += 192) {
        int r  = s / 40, g4 = s - r * 40;
        int w  = g4 * 4;
        int h  = h0 - 5 + r;
        uint4 o = {0u, 0u, 0u, 0u};
        if (h >= 0 && h < 160) {
            const float4 vx = *reinterpret_cast<const float4*>(xb + (size_t)h * WW + w);
            const float4 vy = *reinterpret_cast<const float4*>(yb + (size_t)h * WW + w);
            o.x = ((unsigned int)f2bf(vy.x) << 16) | (unsigned int)f2bf(vx.x);
            o.y = ((unsigned int)f2bf(vy.y) << 16) | (unsigned int)f2bf(vx.y);
            o.z = ((unsigned int)f2bf(vy.z) << 16) | (unsigned int)f2bf(vx.z);
            o.w = ((unsigned int)f2bf(vy.w) << 16) | (unsigned int)f2bf(vx.w);
        }
        *reinterpret_cast<uint4*>(&tile[r][LPAD + w]) = o;
    }
    __syncthreads();

    // ---- compute: LDS u32 taps (2-bitop unpack) + packed-f32 VALU ----
    if (t < 160) {
        const int w = t;
        const size_t outbase = (size_t)n * VOL + (size_t)d * PLANE + w;
        v2f r01[11];          // ring: {conv(x), conv(y)}
        v2f r23[11];          // ring: {conv(x^2)+conv(y^2), conv(xy)} packed

        // Macro-unrolled rows: every ring index is a literal.
#define WSTEP(i) { \
        v2f a01 = {0.f, 0.f}, a23 = {0.f, 0.f}; float a4 = 0.f; \
        _Pragma("unroll") \
        for (int k = 0; k < 5; ++k) { \
            unsigned int u1 = tile[i][w + 3 + k]; \
            unsigned int u2 = tile[i][w + 13 - k]; \
            v2f p1 = { __uint_as_float(u1 << 16), __uint_as_float(u1 & 0xffff0000u) }; \
            v2f p2 = { __uint_as_float(u2 << 16), __uint_as_float(u2 & 0xffff0000u) }; \
            float g = gw.g[k]; v2f g2 = {g, g}; \
            a01 += g2 * (p1 + p2); \
            v2f sq = p1 * p1; \
            sq += p2 * p2; \
            a23 += g2 * sq; \
            float pr = p1.x * p1.y; \
            pr = fmaf(p2.x, p2.y, pr); \
            a4 = fmaf(g, pr, a4); \
        } \
        { \
            unsigned int u = tile[i][w + 8]; \
            v2f p = { __uint_as_float(u << 16), __uint_as_float(u & 0xffff0000u) }; \
            float g = gw.g[5]; v2f g2 = {g, g}; \
            a01 += g2 * p; \
            a23 += g2 * (p * p); \
            a4  = fmaf(g, p.x * p.y, a4); \
        } \
        r01[(i) % 11] = a01; \
        r23[(i) % 11] = (v2f){ a23.x + a23.y, a4 }; \
        if ((i) >= 10) { \
            const int j = (i) - 10; \
            v2f o01 = {0.f, 0.f}, o23 = {0.f, 0.f}; \
            _Pragma("unroll") \
            for (int k = 0; k < 11; ++k) { \
                float g = gw.g[k]; v2f g2 = {g, g}; \
                o01 += g2 * r01[(j + k) % 11]; \
                o23 += g2 * r23[(j + k) % 11]; \
            } \
            size_t oi = outbase + (size_t)(h0 + j) * WW; \
            ushort4 u4; \
            u4.x = f2bf(o01.x); \
            u4.y = f2bf(o01.y); \
            u4.z = f2bf(o23.x); \
            u4.w = f2bf(o23.y); \
            B4[oi] = u4; \
        } }

        WSTEP(0)  WSTEP(1)  WSTEP(2)  WSTEP(3)  WSTEP(4)  WSTEP(5)
        WSTEP(6)  WSTEP(7)  WSTEP(8)  WSTEP(9)  WSTEP(10) WSTEP(11)
        WSTEP(12) WSTEP(13) WSTEP(14) WSTEP(15) WSTEP(16) WSTEP(17)
        WSTEP(18) WSTEP(19) WSTEP(20) WSTEP(21) WSTEP(22) WSTEP(23)
        WSTEP(24) WSTEP(25)
#undef WSTEP
    }
}

// ---------------- Pass B: D-conv + SSIM; raw-u64 rings, PF=8 pipeline ----------------
// CHANGE vs R2: the 11-slice ring stores the RAW bf16x4 u64 exactly as loaded
// (zero deposit cost, 22 regs) instead of unpacked f32 v2f pairs (44 regs).
// Live set drops ~90 -> ~65, which fits the (256,6) cap of 85 VGPR:
// occupancy cap rises 50% -> 75% on a latency-bound kernel (26 us HBM floor,
// ~18 us VALU floor, was ~125 us). Unpack moves into the 11-tap dot
// (+4 bitops/tap) -- harmless when latency-bound.
// Spill tripwire: WRITE_SIZE must stay ~0 (R4's spill signature was 1 GB).
// block 256 (lane -> point p, fully coalesced); grid (100, 4, 4) = 1600 blocks
__global__ __launch_bounds__(256, 6) void k_dssim(
    const u64* __restrict__ B4, double* __restrict__ accum, Gw gw)
{
    const int tid = threadIdx.x;
    const int p   = blockIdx.x * 256 + tid;   // 0..25599
    const int d0  = blockIdx.y * RUN_D;       // 0,40,80,120
    const int n   = blockIdx.z;
    const size_t base = (size_t)n * VOL + p;

    u64 ringU[11];
    float lsum = 0.f;

    // ---- prefetch pipeline: slot q holds slice i with i%PF==q ----
    u64 pf[PF];
    {
        const bool front_ok = (d0 != 0);      // slices 0..4 invalid only in seg 0
#pragma unroll
        for (int q = 0; q < PF; ++q) {
            bool ok = (q >= 5) || front_ok;   // q>=5 -> dd = d0+q-5 <= 122, valid
            pf[q] = 0ull;
            if (ok) {
                size_t idx = base + (size_t)(d0 - 5 + q) * PLANE;
                pf[q] = B4[idx];
            }
        }
    }

#pragma unroll
    for (int i = 0; i < ITERS; ++i) {
        // deposit slice i raw (reg-to-reg move only)
        ringU[i % 11] = pf[i % PF];

        // refill slot with slice i+PF (dd = d0+i+3); back edge block-uniform
        if (i + PF < ITERS) {
            const int dd = d0 + i + 3;        // compile-time offset per unrolled i
            const bool ok = (dd < 160);       // only last segment ever fails
            pf[i % PF] = 0ull;
            if (ok) {
                size_t idx = base + (size_t)dd * PLANE;
                pf[i % PF] = B4[idx];
            }
        }

        if (i >= 10) {
            const int j = i - 10;
            v2f o01 = {0.f, 0.f}, o23 = {0.f, 0.f};
#pragma unroll
            for (int k = 0; k < 11; ++k) {
                u64 v = ringU[(j + k) % 11];
                unsigned int lo = (unsigned int)v;
                unsigned int hi = (unsigned int)(v >> 32);
                v2f a = { __uint_as_float(lo << 16), __uint_as_float(lo & 0xffff0000u) };
                v2f b = { __uint_as_float(hi << 16), __uint_as_float(hi & 0xffff0000u) };
                float g = gw.g[k];
                v2f g2 = {g, g};
                o01 += g2 * a;
                o23 += g2 * b;
            }
            float mu1 = o01.x, mu2 = o01.y;
            float s   = o23.x, e12 = o23.y;
            float m11  = mu1 * mu2;
            float musq = fmaf(mu1, mu1, mu2 * mu2);
            float num = (2.f * m11 + C1f) * (2.f * (e12 - m11) + C2f);
            float den = (musq + C1f) * ((s - musq) + C2f);
            lsum += num * __builtin_amdgcn_rcpf(den);   // rel err ~1e-5 << 1.9e-2 thr
        }
    }

    // 4-wave block reduce, one atomic
    __shared__ float wsum[4];
    const int lane = tid & 63, wi = tid >> 6;
#pragma unroll
    for (int off = 32; off > 0; off >>= 1)
        lsum += __shfl_down(lsum, off, 64);
    if (lane == 0) wsum[wi] = lsum;
    __syncthreads();
    if (tid == 0)
        atomicAdd(accum, (double)(wsum[0] + wsum[1] + wsum[2] + wsum[3]));
}

__global__ void k_final(const double* __restrict__ accum, float* __restrict__ out)
{
    out[0] = (float)(1.0 - accum[0] / ((double)NBATCH * (double)VOL));
}

extern "C" void kernel_launch(void* const* d_in, const int* in_sizes, int n_in,
                              void* d_out, int out_size, void* d_ws, size_t ws_size,
                              hipStream_t stream)
{
    const float* img1 = (const float*)d_in[0];
    const float* img2 = (const float*)d_in[1];
    float* out = (float*)d_out;

    char* ws = (char*)d_ws;
    ushort4* B4 = (ushort4*)ws;                                   // 4*VOL*8B = 131.07 MB
    double* accum = (double*)(ws + (size_t)NBATCH * VOL * 8);

    Gw gw;
    {
        double gd[11], s = 0.0;
        for (int i = 0; i < 11; ++i) {
            double t = (double)(i - 5);
            gd[i] = exp(-(t * t) / (2.0 * 1.5 * 1.5));
            s += gd[i];
        }
        for (int i = 0; i < 11; ++i) gw.g[i] = (float)(gd[i] / s);
    }

    hipMemsetAsync(accum, 0, sizeof(double), stream);

    k_wh   <<<dim3(160 / RUN_H, 160, NBATCH), 192, 0, stream>>>(img1, img2, B4, gw);
    k_dssim<<<dim3(PLANE / 256, 160 / RUN_D, NBATCH), 256, 0, stream>>>(
        (const u64*)B4, accum, gw);
    k_final<<<1, 1, 0, stream>>>(accum, out);
}

// Round 7
// 275.167 us; speedup vs baseline: 2.0442x; 2.0442x over previous
//
#include <hip/hip_runtime.h>
#include <hip/hip_bf16.h>
#include <math.h>

#define WW     160
#define NBATCH 4
#define VOL    (160*160*160)      // 4,096,000
#define PLANE  (160*160)

#define C1f 0.0001f
#define C2f 0.0009f

#define RUN_H 16                  // h outputs per k_wh block
#define NROWS (RUN_H + 10)        // 26 rows staged
#define LDW   176                 // padded cols: [0..4]=0, [5..164]=data, [165..175]=0
#define RUN_D 40                  // d outputs per k_dssim block (4 segments)
#define ITERS (RUN_D + 10)        // 50
#define PF    16                  // prefetch slots; 16 loads in flight per wave

typedef float v2f __attribute__((ext_vector_type(2)));

struct Gw { float g[11]; };

__device__ __forceinline__ float bf2f(unsigned short u) {
    return __uint_as_float(((unsigned int)u) << 16);
}
__device__ __forceinline__ unsigned short f2bf(float f) {
    __hip_bfloat16 h = __float2bfloat16(f);   // RNE
    return *reinterpret_cast<unsigned short*>(&h);
}

// ---------------- Pass A: W+H conv fused; bf16x2-packed LDS tile ----------------
// R2 VERBATIM (measured 148.3 us, session best for this pass).
// R6's vectorized-staging rewrite is suspected ~200 us (562 total - 350 k_dssim)
// -- reverted wholesale. Lesson: this pass's 148 is structural (VALU ~66% busy,
// scalar staging included); further k_wh work needs isolated counters first.
// block 192 (3 waves; threads 0..159 compute, all 192 load)
// grid (10, d=160, batch=4) = 6400 blocks; LDS 18.3 KB -> 8 blocks/CU.
__global__ __launch_bounds__(192, 4) void k_wh(
    const float* __restrict__ x, const float* __restrict__ y,
    ushort4* __restrict__ B4, Gw gw)
{
    __shared__ unsigned int tile[NROWS][LDW];   // 26*176*4 = 18.3 KB
    const int t  = threadIdx.x;
    const int h0 = blockIdx.x * RUN_H;
    const int d  = blockIdx.y;
    const int n  = blockIdx.z;

    const float* xb = x + (size_t)n * VOL + (size_t)d * PLANE;
    const float* yb = y + (size_t)n * VOL + (size_t)d * PLANE;

    // ---- fill tile: independent coalesced loads, pack bf16(y)<<16 | bf16(x) ----
#pragma unroll 4
    for (int s = t; s < NROWS * LDW; s += 192) {
        int r = s / LDW, c = s - r * LDW;
        int h = h0 - 5 + r;
        int w = c - 5;
        float vx = 0.f, vy = 0.f;
        if (h >= 0 && h < 160 && w >= 0 && w < 160) {
            size_t idx = (size_t)h * WW + w;
            vx = xb[idx];
            vy = yb[idx];
        }
        tile[r][c] = ((unsigned int)f2bf(vy) << 16) | (unsigned int)f2bf(vx);
    }
    __syncthreads();

    // ---- compute: LDS u32 taps (2-bitop unpack) + packed-f32 VALU ----
    if (t < 160) {
        const int w = t;
        const size_t outbase = (size_t)n * VOL + (size_t)d * PLANE + w;
        v2f r01[11];          // ring: {conv(x), conv(y)}
        v2f r23[11];          // ring: {conv(x^2)+conv(y^2), conv(xy)} packed

        // Macro-unrolled rows: every ring index is a literal.
#define WSTEP(i) { \
        v2f a01 = {0.f, 0.f}, a23 = {0.f, 0.f}; float a4 = 0.f; \
        _Pragma("unroll") \
        for (int k = 0; k < 5; ++k) { \
            unsigned int u1 = tile[i][w + k]; \
            unsigned int u2 = tile[i][w + 10 - k]; \
            v2f p1 = { __uint_as_float(u1 << 16), __uint_as_float(u1 & 0xffff0000u) }; \
            v2f p2 = { __uint_as_float(u2 << 16), __uint_as_float(u2 & 0xffff0000u) }; \
            float g = gw.g[k]; v2f g2 = {g, g}; \
            a01 += g2 * (p1 + p2); \
            v2f sq = p1 * p1; \
            sq += p2 * p2; \
            a23 += g2 * sq; \
            float pr = p1.x * p1.y; \
            pr = fmaf(p2.x, p2.y, pr); \
            a4 = fmaf(g, pr, a4); \
        } \
        { \
            unsigned int u = tile[i][w + 5]; \
            v2f p = { __uint_as_float(u << 16), __uint_as_float(u & 0xffff0000u) }; \
            float g = gw.g[5]; v2f g2 = {g, g}; \
            a01 += g2 * p; \
            a23 += g2 * (p * p); \
            a4  = fmaf(g, p.x * p.y, a4); \
        } \
        r01[(i) % 11] = a01; \
        r23[(i) % 11] = (v2f){ a23.x + a23.y, a4 }; \
        if ((i) >= 10) { \
            const int j = (i) - 10; \
            v2f o01 = {0.f, 0.f}, o23 = {0.f, 0.f}; \
            _Pragma("unroll") \
            for (int k = 0; k < 11; ++k) { \
                float g = gw.g[k]; v2f g2 = {g, g}; \
                o01 += g2 * r01[(j + k) % 11]; \
                o23 += g2 * r23[(j + k) % 11]; \
            } \
            size_t oi = outbase + (size_t)(h0 + j) * WW; \
            ushort4 u4; \
            u4.x = f2bf(o01.x); \
            u4.y = f2bf(o01.y); \
            u4.z = f2bf(o23.x); \
            u4.w = f2bf(o23.y); \
            B4[oi] = u4; \
        } }

        WSTEP(0)  WSTEP(1)  WSTEP(2)  WSTEP(3)  WSTEP(4)  WSTEP(5)
        WSTEP(6)  WSTEP(7)  WSTEP(8)  WSTEP(9)  WSTEP(10) WSTEP(11)
        WSTEP(12) WSTEP(13) WSTEP(14) WSTEP(15) WSTEP(16) WSTEP(17)
        WSTEP(18) WSTEP(19) WSTEP(20) WSTEP(21) WSTEP(22) WSTEP(23)
        WSTEP(24) WSTEP(25)
#undef WSTEP
    }
}

// ---------------- Pass B: D-conv + SSIM; 4ch, PF=16 pipeline, rcp ----------------
// R2 structure verbatim; ONE change: PF 8 -> 16.
// Diagnosis: at (256,4) this kernel is concurrency-bound, not VALU-bound
// (VALU floor ~15 us, HBM floor ~26 us, measured ~121 us; 8x8B=64B in flight
// per thread -> 1.4 TB/s achieved). Doubling in-flight loads doubles memory
// concurrency without touching launch bounds (R4/R6 proved caps <=102 spill).
// Reg math: 44 ring + 32 pf + ~30 temps ~ 106 < 128 cap.
// Spill tripwire: WRITE_SIZE must stay ~0.05 MB (spill signature = 100s of MB).
// block 256 (lane -> point p, fully coalesced); grid (100, 4, 4) = 1600 blocks
__global__ __launch_bounds__(256, 4) void k_dssim(
    const ushort4* __restrict__ B4, double* __restrict__ accum, Gw gw)
{
    const int tid = threadIdx.x;
    const int p   = blockIdx.x * 256 + tid;   // 0..25599
    const int d0  = blockIdx.y * RUN_D;       // 0,40,80,120
    const int n   = blockIdx.z;
    const size_t base = (size_t)n * VOL + p;

    v2f ring01[11], ring23[11];
    float lsum = 0.f;

    // ---- prefetch pipeline: slot q holds slice i with i%PF==q ----
    // q covers slices d0-5 .. d0+10; q>=5 -> dd = d0+q-5 <= 130 always valid.
    ushort4 pf[PF];
    {
        const bool front_ok = (d0 != 0);      // slices 0..4 invalid only in seg 0
#pragma unroll
        for (int q = 0; q < PF; ++q) {
            bool ok = (q >= 5) || front_ok;
            pf[q] = make_ushort4(0, 0, 0, 0);
            if (ok) {
                size_t idx = base + (size_t)(d0 - 5 + q) * PLANE;
                pf[q] = B4[idx];
            }
        }
    }

#pragma unroll
    for (int i = 0; i < ITERS; ++i) {
        // consume slice i
        ushort4 c4 = pf[i % PF];
        ring01[i%11] = (v2f){ bf2f(c4.x), bf2f(c4.y) };
        ring23[i%11] = (v2f){ bf2f(c4.z), bf2f(c4.w) };

        // refill slot with slice i+PF (dd = d0+i+11); back edge block-uniform
        if (i + PF < ITERS) {
            const int dd = d0 + i + 11;       // compile-time offset per unrolled i
            const bool ok = (dd < 160);       // only last segment ever fails
            pf[i % PF] = make_ushort4(0, 0, 0, 0);
            if (ok) {
                size_t idx = base + (size_t)dd * PLANE;
                pf[i % PF] = B4[idx];
            }
        }

        if (i >= 10) {
            const int j = i - 10;
            v2f o01 = {0.f, 0.f}, o23 = {0.f, 0.f};
#pragma unroll
            for (int k = 0; k < 11; ++k) {
                float g = gw.g[k];
                v2f g2 = {g, g};
                o01 += g2 * ring01[(j + k) % 11];
                o23 += g2 * ring23[(j + k) % 11];
            }
            float mu1 = o01.x, mu2 = o01.y;
            float s   = o23.x, e12 = o23.y;
            float m11  = mu1 * mu2;
            float musq = fmaf(mu1, mu1, mu2 * mu2);
            float num = (2.f * m11 + C1f) * (2.f * (e12 - m11) + C2f);
            float den = (musq + C1f) * ((s - musq) + C2f);
            lsum += num * __builtin_amdgcn_rcpf(den);   // rel err ~1e-5 << 1.9e-2 thr
        }
    }

    // 4-wave block reduce, one atomic
    __shared__ float wsum[4];
    const int lane = tid & 63, wi = tid >> 6;
#pragma unroll
    for (int off = 32; off > 0; off >>= 1)
        lsum += __shfl_down(lsum, off, 64);
    if (lane == 0) wsum[wi] = lsum;
    __syncthreads();
    if (tid == 0)
        atomicAdd(accum, (double)(wsum[0] + wsum[1] + wsum[2] + wsum[3]));
}

__global__ void k_final(const double* __restrict__ accum, float* __restrict__ out)
{
    out[0] = (float)(1.0 - accum[0] / ((double)NBATCH * (double)VOL));
}

extern "C" void kernel_launch(void* const* d_in, const int* in_sizes, int n_in,
                              void* d_out, int out_size, void* d_ws, size_t ws_size,
                              hipStream_t stream)
{
    const float* img1 = (const float*)d_in[0];
    const float* img2 = (const float*)d_in[1];
    float* out = (float*)d_out;

    char* ws = (char*)d_ws;
    ushort4* B4 = (ushort4*)ws;                                   // 4*VOL*8B = 131.07 MB
    double* accum = (double*)(ws + (size_t)NBATCH * VOL * 8);

    Gw gw;
    {
        double gd[11], s = 0.0;
        for (int i = 0; i < 11; ++i) {
            double t = (double)(i - 5);
            gd[i] = exp(-(t * t) / (2.0 * 1.5 * 1.5));
            s += gd[i];
        }
        for (int i = 0; i < 11; ++i) gw.g[i] = (float)(gd[i] / s);
    }

    hipMemsetAsync(accum, 0, sizeof(double), stream);

    k_wh   <<<dim3(160 / RUN_H, 160, NBATCH), 192, 0, stream>>>(img1, img2, B4, gw);
    k_dssim<<<dim3(PLANE / 256, 160 / RUN_D, NBATCH), 256, 0, stream>>>(B4, accum, gw);
    k_final<<<1, 1, 0, stream>>>(accum, out);
}